// Round 3
// baseline (251.879 us; speedup 1.0000x reference)
//
#include <hip/hip_runtime.h>
#include <math.h>

#define WSZ 11
#define PAD 5
#define TX 64                // tile width (output cols per block)
#define TY 16                // rows per s-tile
#define NY 9                 // s-tiles per block: 144 rows/block, 2160/144 = 15
#define IY (TY + 2*PAD)      // 26
#define RX 4                 // h-pass: 4 output px per task
#define CHX (TX / RX)        // 16 x-chunks per row
#define NTASK0 (IY * CHX)    // 416 tasks (s==0: full 26 rows)
#define NTASK1 (TY * CHX)    // 256 tasks (s>0) == blockDim -> zero idle lanes
#define SEG (RX + 2*PAD)     // 14 input floats per task
#define RY 4                 // v-pass rows per thread (4 groups x 4 = 16)
#define SA 65                // sHA row stride in float4 (260 dw == 4 mod 32)

typedef float v2f __attribute__((ext_vector_type(2)));

struct W11 { float w[WSZ]; };

// R7 macro-structure + R8 register staging + R9 packed f32 + R10 rolling halo
// + R11 sum/diff reformulation (4 conv channels, 2 pk_fma/tap).
// R12: TX=64/TY=16/NY=9 re-tiling. Fixes three structural inefficiencies at
// once: (1) Phase A s>0 now has EXACTLY 256 tasks -> no idle warp (was 192
// tasks / 256 threads = 25% idle in 5/6 tiles); (2) Phase B is 64 cols x 4
// y-groups x RY=4 -> 3.5 LDS row-reads/output (was 4.33), and each wave reads
// one contiguous 1024B row segment; (3) x-halo fetch 1.25x (was 1.5x).
// LDS 27.1 KB -> 5-6 blocks/CU, about the same effective residency.
__global__ __launch_bounds__(256, 4) void ssim_l1_kernel(
    const float* __restrict__ pred, const float* __restrict__ targ,
    W11 wt, float2* __restrict__ partials)
{
    constexpr int H = 2160, W = 3840;
    __shared__ float4 sHA[IY][SA];   // {hs, hd, hss, hdd}   27.04 KB

    const int c    = blockIdx.z;
    const int gx0  = blockIdx.x * TX;
    const int base = blockIdx.y * (TY * NY);   // first output row of block
    const size_t plane = (size_t)H * W;
    const float* p = pred + (size_t)c * plane;
    const float* t = targ + (size_t)c * plane;

    const int tid = threadIdx.x;
    v2f loss_acc = {0.f, 0.f};       // .x = ssim, .y = l1
    const float C1v = 0.0001f, C2v = 0.0009f;

    const int oxB  = tid & 63;             // column (one wave = one row set)
    const int oy0B = (tid >> 6) * RY;      // 4 y-groups x RY=4 rows
    const bool xfast = (blockIdx.x >= 1) && (blockIdx.x <= (W / TX) - 2);

    for (int s = 0; s < NY; ++s) {
        // ============ Phase A0 (s>0): shift halo rows 16..25 -> 0..9 =======
        if (s > 0) {
            for (int i = tid; i < 2 * PAD * TX; i += 256) {   // 640 float4
                const int dr = i >> 6, cc = i & 63;
                sHA[dr][cc] = sHA[dr + TY][cc];
            }
            __syncthreads();
        }

        // ============ Phase A: horizontal 11-tap, global -> LDS ============
        const int ntask  = (s == 0) ? NTASK0 : NTASK1;
        const int rowoff = (s == 0) ? 0 : 2 * PAD;
        const int gyA    = base + TY * s - PAD;      // gy = gyA + rr
        for (int task = tid; task < ntask; task += 256) {
            const int r  = task >> 4;                // 16 chunks per row
            const int cx = task & 15;
            const int rr = rowoff + r;               // LDS buffer row
            const int gy = gyA + rr;                 // global image row
            const int gxs = gx0 + cx * RX - PAD;     // input window e=0..13
            const bool rowok   = (gy >= 0) && (gy < H);
            const bool own_row = (gy >= base) && (gy < base + TY * NY);

            // 5 aligned float4 per image covering gxs-3 .. gxs+16 (registers)
            float4 P[5], T[5];
            if (rowok && xfast) {
                const float4* p4 = (const float4*)(p + (size_t)gy * W + (gxs - 3));
                const float4* t4 = (const float4*)(t + (size_t)gy * W + (gxs - 3));
                #pragma unroll
                for (int i = 0; i < 5; ++i) { P[i] = p4[i]; T[i] = t4[i]; }
            } else if (rowok) {
                const size_t rowoff2 = (size_t)gy * W;
                #pragma unroll
                for (int i = 0; i < 5; ++i) {
                    float pe[4], te[4];
                    #pragma unroll
                    for (int q = 0; q < 4; ++q) {
                        int gx = gxs - 3 + 4 * i + q;
                        bool ok = (gx >= 0) && (gx < W);
                        pe[q] = ok ? p[rowoff2 + gx] : 0.f;
                        te[q] = ok ? t[rowoff2 + gx] : 0.f;
                    }
                    P[i] = make_float4(pe[0], pe[1], pe[2], pe[3]);
                    T[i] = make_float4(te[0], te[1], te[2], te[3]);
                }
            } else {
                #pragma unroll
                for (int i = 0; i < 5; ++i) {
                    P[i] = make_float4(0.f, 0.f, 0.f, 0.f);
                    T[i] = make_float4(0.f, 0.f, 0.f, 0.f);
                }
            }

            v2f h_sd[RX], h_qq[RX];
            #pragma unroll
            for (int j = 0; j < RX; ++j) {
                h_sd[j] = (v2f){0.f, 0.f};
                h_qq[j] = (v2f){0.f, 0.f};
            }
            #pragma unroll
            for (int e = 0; e < SEG; ++e) {
                const int ii = (e + 3) >> 2, qq = (e + 3) & 3;
                const float pe = (qq == 0) ? P[ii].x : (qq == 1) ? P[ii].y
                                : (qq == 2) ? P[ii].z : P[ii].w;
                const float te = (qq == 0) ? T[ii].x : (qq == 1) ? T[ii].y
                                : (qq == 2) ? T[ii].z : T[ii].w;
                v2f vsd; vsd.x = pe + te; vsd.y = pe - te;
                const v2f vsq = vsd * vsd;          // v_pk_mul_f32
                #pragma unroll
                for (int j = 0; j < RX; ++j) {
                    const int k = e - j;
                    if (k >= 0 && k < WSZ) {
                        const float wv = wt.w[k];
                        h_sd[j] += wv * vsd;        // v_pk_fma_f32
                        h_qq[j] += wv * vsq;        // v_pk_fma_f32
                    }
                }
                // L1 on owned pixels: d = p - t already in vsd.y
                if (e >= PAD && e < PAD + RX && own_row)
                    loss_acc.y += fabsf(vsd.y);
            }
            const int xb = cx * RX;
            #pragma unroll
            for (int j = 0; j < RX; ++j)
                sHA[rr][xb + j] = make_float4(h_sd[j].x, h_sd[j].y,
                                              h_qq[j].x, h_qq[j].y);
        }
        __syncthreads();

        // ============ Phase B: vertical 11-tap + SSIM ======================
        {
            v2f mu[RY], qq[RY];
            #pragma unroll
            for (int j = 0; j < RY; ++j) {
                mu[j] = (v2f){0.f, 0.f};
                qq[j] = (v2f){0.f, 0.f};
            }
            #pragma unroll
            for (int k = 0; k < RY + 2 * PAD; ++k) {   // 14 contiguous reads
                const float4 f = sHA[oy0B + k][oxB];
                v2f fsd; fsd.x = f.x; fsd.y = f.y;
                v2f fsq; fsq.x = f.z; fsq.y = f.w;
                #pragma unroll
                for (int j = 0; j < RY; ++j) {
                    const int kk = k - j;
                    if (kk >= 0 && kk < WSZ) {
                        const float wv = wt.w[kk];
                        mu[j] += wv * fsd;          // v_pk_fma_f32
                        qq[j] += wv * fsq;          // v_pk_fma_f32
                    }
                }
            }
            #pragma unroll
            for (int j = 0; j < RY; ++j) {
                const v2f musq = mu[j] * mu[j];     // (S^2, D^2)  v_pk_mul
                const v2f rr2  = qq[j] - musq;      // (Qs-S^2, Qd-D^2)
                const float a    = 0.5f * (musq.x - musq.y) + C1v;
                const float b    = 0.5f * (rr2.x - rr2.y) + C2v;
                const float cden = 0.5f * (musq.x + musq.y) + C1v;
                const float dden = 0.5f * (rr2.x + rr2.y) + C2v;
                loss_acc.x += (a * b) * __builtin_amdgcn_rcpf(cden * dden);
            }
        }
        __syncthreads();   // Phase B reads done before next shift/Phase A
    }

    // ============ block reduction -> contention-free partial ================
    #pragma unroll
    for (int off = 32; off > 0; off >>= 1) {
        loss_acc.x += __shfl_down(loss_acc.x, off, 64);
        loss_acc.y += __shfl_down(loss_acc.y, off, 64);
    }
    __shared__ float red[2][4];
    const int lane = tid & 63;
    const int wid  = tid >> 6;
    if (lane == 0) { red[0][wid] = loss_acc.x; red[1][wid] = loss_acc.y; }
    __syncthreads();
    if (tid == 0) {
        const float sv = red[0][0] + red[0][1] + red[0][2] + red[0][3];
        const float lv = red[1][0] + red[1][1] + red[1][2] + red[1][3];
        const int bid = (blockIdx.z * gridDim.y + blockIdx.y) * gridDim.x + blockIdx.x;
        partials[bid] = make_float2(sv, lv);
    }
}

__global__ __launch_bounds__(256) void finalize_kernel(
    const float2* __restrict__ partials, int n,
    float* __restrict__ out, double invN)
{
    const int tid = threadIdx.x;
    double s = 0.0, l = 0.0;
    for (int i = tid; i < n; i += 256) {
        float2 v = partials[i];
        s += (double)v.x;
        l += (double)v.y;
    }
    #pragma unroll
    for (int off = 32; off > 0; off >>= 1) {
        s += __shfl_down(s, off, 64);
        l += __shfl_down(l, off, 64);
    }
    __shared__ double rs[4], rl[4];
    const int lane = tid & 63, wid = tid >> 6;
    if (lane == 0) { rs[wid] = s; rl[wid] = l; }
    __syncthreads();
    if (tid == 0) {
        const double st = rs[0] + rs[1] + rs[2] + rs[3];
        const double lt = rl[0] + rl[1] + rl[2] + rl[3];
        out[0] = (float)(0.8 * lt * invN + 0.2 * (1.0 - st * invN));
    }
}

extern "C" void kernel_launch(void* const* d_in, const int* in_sizes, int n_in,
                              void* d_out, int out_size, void* d_ws, size_t ws_size,
                              hipStream_t stream)
{
    const float* pred = (const float*)d_in[0];
    const float* targ = (const float*)d_in[1];
    float* out = (float*)d_out;
    float2* partials = (float2*)d_ws;

    const int C = 3, H = 2160, W = 3840;

    W11 wt;
    double g[WSZ], sg = 0.0;
    for (int i = 0; i < WSZ; ++i) {
        double d = (double)i - (WSZ / 2);
        g[i] = exp(-(d * d) / (2.0 * 1.5 * 1.5));
        sg += g[i];
    }
    for (int i = 0; i < WSZ; ++i) wt.w[i] = (float)(g[i] / sg);

    dim3 grid(W / TX, H / (TY * NY), C);   // 60 x 15 x 3 = 2700 blocks
    ssim_l1_kernel<<<grid, 256, 0, stream>>>(pred, targ, wt, partials);

    const int nblocks = (W / TX) * (H / (TY * NY)) * C;
    double invN = 1.0 / ((double)C * (double)H * (double)W);
    finalize_kernel<<<1, 256, 0, stream>>>(partials, nblocks, out, invN);
}

// Round 4
// 247.144 us; speedup vs baseline: 1.0192x; 1.0192x over previous
//
#include <hip/hip_runtime.h>
#include <math.h>

#define WSZ 11
#define PAD 5
#define TX 64                // tile width (output cols per block)
#define TY 24                // rows per s-tile
#define NY 6                 // 144 rows/block, 2160/144 = 15
#define IY (TY + 2*PAD)      // 34
#define RX 4                 // h-pass: 4 output px per task
#define CHX (TX / RX)        // 16 x-chunks per row
#define NTASK0 (IY * CHX)    // 544 tasks (s==0)
#define NTASK1 (TY * CHX)    // 384 tasks (s>0)
#define SEG (RX + 2*PAD)     // 14 input floats per task
#define RY 3                 // v-pass rows per thread (8 groups x 3 = 24)
#define SA 65                // sHA row stride in float4 (260 dw == 4 mod 32)
#define NTHR 512

typedef float v2f __attribute__((ext_vector_type(2)));

struct W11 { float w[WSZ]; };

// R10 rolling halo + R11 sum/diff (4 channels, 2 pk_fma/tap) + R13 geometry.
// R12 lesson: TX=64 wins fetch (205 MB ~= 1.03x ideal) but 27 KB LDS at 256
// threads capped residency at 5 blocks/CU -> regressed. R13 keeps TX=64 and
// restores full residency with 512-thread blocks: LDS 35.4 KB x 4 blocks/CU
// = 141.6/160 KB, 4 x 8 waves = 32 waves/CU (100% cap). Per-pixel VALU, LDS
// traffic and shift cost identical to the best R11 config (RX=4, RY=3);
// barrier density halves; grid 2700.
__global__ __launch_bounds__(NTHR, 8) void ssim_l1_kernel(
    const float* __restrict__ pred, const float* __restrict__ targ,
    W11 wt, float2* __restrict__ partials)
{
    constexpr int H = 2160, W = 3840;
    __shared__ float4 sHA[IY][SA];   // {hs, hd, hss, hdd}   35.36 KB

    const int c    = blockIdx.z;
    const int gx0  = blockIdx.x * TX;
    const int base = blockIdx.y * (TY * NY);   // first output row of block
    const size_t plane = (size_t)H * W;
    const float* p = pred + (size_t)c * plane;
    const float* t = targ + (size_t)c * plane;

    const int tid = threadIdx.x;
    v2f loss_acc = {0.f, 0.f};       // .x = ssim, .y = l1
    const float C1v = 0.0001f, C2v = 0.0009f;

    const int oxB  = tid & 63;             // column (wave reads 1024B rows)
    const int oy0B = (tid >> 6) * RY;      // 8 y-groups x RY=3 rows
    const bool xfast = (blockIdx.x >= 1) && (blockIdx.x <= (W / TX) - 2);

    for (int s = 0; s < NY; ++s) {
        // ============ Phase A0 (s>0): shift halo rows 24..33 -> 0..9 =======
        if (s > 0) {
            for (int i = tid; i < 2 * PAD * TX; i += NTHR) {   // 640 float4
                const int dr = i >> 6, cc = i & 63;
                sHA[dr][cc] = sHA[dr + TY][cc];
            }
            __syncthreads();
        }

        // ============ Phase A: horizontal 11-tap, global -> LDS ============
        const int ntask  = (s == 0) ? NTASK0 : NTASK1;
        const int rowoff = (s == 0) ? 0 : 2 * PAD;
        const int gyA    = base + TY * s - PAD;      // gy = gyA + rr
        for (int task = tid; task < ntask; task += NTHR) {
            const int r  = task >> 4;                // 16 chunks per row
            const int cx = task & 15;
            const int rr = rowoff + r;               // LDS buffer row
            const int gy = gyA + rr;                 // global image row
            const int gxs = gx0 + cx * RX - PAD;     // input window e=0..13
            const bool rowok   = (gy >= 0) && (gy < H);
            const bool own_row = (gy >= base) && (gy < base + TY * NY);

            // 5 aligned float4 per image covering gxs-3 .. gxs+16 (registers)
            float4 P[5], T[5];
            if (rowok && xfast) {
                const float4* p4 = (const float4*)(p + (size_t)gy * W + (gxs - 3));
                const float4* t4 = (const float4*)(t + (size_t)gy * W + (gxs - 3));
                #pragma unroll
                for (int i = 0; i < 5; ++i) { P[i] = p4[i]; T[i] = t4[i]; }
            } else if (rowok) {
                const size_t rowoff2 = (size_t)gy * W;
                #pragma unroll
                for (int i = 0; i < 5; ++i) {
                    float pe[4], te[4];
                    #pragma unroll
                    for (int q = 0; q < 4; ++q) {
                        int gx = gxs - 3 + 4 * i + q;
                        bool ok = (gx >= 0) && (gx < W);
                        pe[q] = ok ? p[rowoff2 + gx] : 0.f;
                        te[q] = ok ? t[rowoff2 + gx] : 0.f;
                    }
                    P[i] = make_float4(pe[0], pe[1], pe[2], pe[3]);
                    T[i] = make_float4(te[0], te[1], te[2], te[3]);
                }
            } else {
                #pragma unroll
                for (int i = 0; i < 5; ++i) {
                    P[i] = make_float4(0.f, 0.f, 0.f, 0.f);
                    T[i] = make_float4(0.f, 0.f, 0.f, 0.f);
                }
            }

            v2f h_sd[RX], h_qq[RX];
            #pragma unroll
            for (int j = 0; j < RX; ++j) {
                h_sd[j] = (v2f){0.f, 0.f};
                h_qq[j] = (v2f){0.f, 0.f};
            }
            #pragma unroll
            for (int e = 0; e < SEG; ++e) {
                const int ii = (e + 3) >> 2, qq = (e + 3) & 3;
                const float pe = (qq == 0) ? P[ii].x : (qq == 1) ? P[ii].y
                                : (qq == 2) ? P[ii].z : P[ii].w;
                const float te = (qq == 0) ? T[ii].x : (qq == 1) ? T[ii].y
                                : (qq == 2) ? T[ii].z : T[ii].w;
                v2f vsd; vsd.x = pe + te; vsd.y = pe - te;
                const v2f vsq = vsd * vsd;          // v_pk_mul_f32
                #pragma unroll
                for (int j = 0; j < RX; ++j) {
                    const int k = e - j;
                    if (k >= 0 && k < WSZ) {
                        const float wv = wt.w[k];
                        h_sd[j] += wv * vsd;        // v_pk_fma_f32
                        h_qq[j] += wv * vsq;        // v_pk_fma_f32
                    }
                }
                // L1 on owned pixels: d = p - t already in vsd.y
                if (e >= PAD && e < PAD + RX && own_row)
                    loss_acc.y += fabsf(vsd.y);
            }
            const int xb = cx * RX;
            #pragma unroll
            for (int j = 0; j < RX; ++j)
                sHA[rr][xb + j] = make_float4(h_sd[j].x, h_sd[j].y,
                                              h_qq[j].x, h_qq[j].y);
        }
        __syncthreads();

        // ============ Phase B: vertical 11-tap + SSIM ======================
        {
            v2f mu[RY], qq[RY];
            #pragma unroll
            for (int j = 0; j < RY; ++j) {
                mu[j] = (v2f){0.f, 0.f};
                qq[j] = (v2f){0.f, 0.f};
            }
            #pragma unroll
            for (int k = 0; k < RY + 2 * PAD; ++k) {   // 13 contiguous reads
                const float4 f = sHA[oy0B + k][oxB];
                v2f fsd; fsd.x = f.x; fsd.y = f.y;
                v2f fsq; fsq.x = f.z; fsq.y = f.w;
                #pragma unroll
                for (int j = 0; j < RY; ++j) {
                    const int kk = k - j;
                    if (kk >= 0 && kk < WSZ) {
                        const float wv = wt.w[kk];
                        mu[j] += wv * fsd;          // v_pk_fma_f32
                        qq[j] += wv * fsq;          // v_pk_fma_f32
                    }
                }
            }
            #pragma unroll
            for (int j = 0; j < RY; ++j) {
                const v2f musq = mu[j] * mu[j];     // (S^2, D^2)  v_pk_mul
                const v2f rr2  = qq[j] - musq;      // (Qs-S^2, Qd-D^2)
                const float a    = 0.5f * (musq.x - musq.y) + C1v;
                const float b    = 0.5f * (rr2.x - rr2.y) + C2v;
                const float cden = 0.5f * (musq.x + musq.y) + C1v;
                const float dden = 0.5f * (rr2.x + rr2.y) + C2v;
                loss_acc.x += (a * b) * __builtin_amdgcn_rcpf(cden * dden);
            }
        }
        __syncthreads();   // Phase B reads done before next shift/Phase A
    }

    // ============ block reduction -> contention-free partial ================
    #pragma unroll
    for (int off = 32; off > 0; off >>= 1) {
        loss_acc.x += __shfl_down(loss_acc.x, off, 64);
        loss_acc.y += __shfl_down(loss_acc.y, off, 64);
    }
    __shared__ float red[2][8];
    const int lane = tid & 63;
    const int wid  = tid >> 6;
    if (lane == 0) { red[0][wid] = loss_acc.x; red[1][wid] = loss_acc.y; }
    __syncthreads();
    if (tid == 0) {
        float sv = 0.f, lv = 0.f;
        #pragma unroll
        for (int wq = 0; wq < NTHR / 64; ++wq) { sv += red[0][wq]; lv += red[1][wq]; }
        const int bid = (blockIdx.z * gridDim.y + blockIdx.y) * gridDim.x + blockIdx.x;
        partials[bid] = make_float2(sv, lv);
    }
}

__global__ __launch_bounds__(256) void finalize_kernel(
    const float2* __restrict__ partials, int n,
    float* __restrict__ out, double invN)
{
    const int tid = threadIdx.x;
    double s = 0.0, l = 0.0;
    for (int i = tid; i < n; i += 256) {
        float2 v = partials[i];
        s += (double)v.x;
        l += (double)v.y;
    }
    #pragma unroll
    for (int off = 32; off > 0; off >>= 1) {
        s += __shfl_down(s, off, 64);
        l += __shfl_down(l, off, 64);
    }
    __shared__ double rs[4], rl[4];
    const int lane = tid & 63, wid = tid >> 6;
    if (lane == 0) { rs[wid] = s; rl[wid] = l; }
    __syncthreads();
    if (tid == 0) {
        const double st = rs[0] + rs[1] + rs[2] + rs[3];
        const double lt = rl[0] + rl[1] + rl[2] + rl[3];
        out[0] = (float)(0.8 * lt * invN + 0.2 * (1.0 - st * invN));
    }
}

extern "C" void kernel_launch(void* const* d_in, const int* in_sizes, int n_in,
                              void* d_out, int out_size, void* d_ws, size_t ws_size,
                              hipStream_t stream)
{
    const float* pred = (const float*)d_in[0];
    const float* targ = (const float*)d_in[1];
    float* out = (float*)d_out;
    float2* partials = (float2*)d_ws;

    const int C = 3, H = 2160, W = 3840;

    W11 wt;
    double g[WSZ], sg = 0.0;
    for (int i = 0; i < WSZ; ++i) {
        double d = (double)i - (WSZ / 2);
        g[i] = exp(-(d * d) / (2.0 * 1.5 * 1.5));
        sg += g[i];
    }
    for (int i = 0; i < WSZ; ++i) wt.w[i] = (float)(g[i] / sg);

    dim3 grid(W / TX, H / (TY * NY), C);   // 60 x 15 x 3 = 2700 blocks
    ssim_l1_kernel<<<grid, NTHR, 0, stream>>>(pred, targ, wt, partials);

    const int nblocks = (W / TX) * (H / (TY * NY)) * C;
    double invN = 1.0 / ((double)C * (double)H * (double)W);
    finalize_kernel<<<1, 256, 0, stream>>>(partials, nblocks, out, invN);
}